// Round 8
// baseline (184.508 us; speedup 1.0000x reference)
//
#include <hip/hip_runtime.h>

// GrCNet attention layer — CSR gather formulation.
//   u[n] = W1 x[n], v[n] = W2 x[n]   (a = [W1 | W2], [64,128] row-major)
//   su[n] = u[n].a2, sv[n] = v[n].a2
//   edge e: g = 0.5*(G[s,t]+G[d,t]); ee = exp(-lrelu(g*(su[s]+sv[d]))); w = ee*g
//   CSR-by-src stores packed int4 (d, w, ee, 0)
//   h[n] = elu( ((Σw)·u[n] + Σ w·v[d]) / Σee )
//
// Round 8: aggregate reads csr[j] at a WAVE-UNIFORM address (broadcast load)
// instead of coalesced-load + 2x ds_bpermute per entry; sumw/sumee become
// wave-uniform (no final cross-lane reductions). scan_add folded into
// consumers (edge_place/aggregate add blocksums[i/TILE] themselves).

#define LRELU_ALPHA 0.2f
#define SCAN_BLOCK 256
#define SCAN_ITEMS 8
#define SCAN_TILE (SCAN_BLOCK * SCAN_ITEMS)  // 2048

__global__ __launch_bounds__(256) void node_transform_kernel(
    const float* __restrict__ x, const float* __restrict__ a,
    const float* __restrict__ a2,
    float* __restrict__ u, float* __restrict__ v,
    float* __restrict__ su, float* __restrict__ sv,
    int* __restrict__ count, int N)
{
    __shared__ float a_lds[64][129];
    for (int idx = threadIdx.x; idx < 64 * 128; idx += 256)
        a_lds[idx >> 7][idx & 127] = a[idx];
    __syncthreads();

    const int wave = threadIdx.x >> 6;
    const int lane = threadIdx.x & 63;
    const int n = blockIdx.x * 4 + wave;
    if (n >= N) return;

    if (lane == 0) count[n] = 0;

    const float a2v = a2[lane];
    const float* xr = x + (size_t)n * 64;
    float uo = 0.f, vo = 0.f;
#pragma unroll 8
    for (int i = 0; i < 64; ++i) {
        const float xi = xr[i];
        uo += xi * a_lds[lane][i];
        vo += xi * a_lds[lane][64 + i];
    }
    u[(size_t)n * 64 + lane] = uo;
    v[(size_t)n * 64 + lane] = vo;

    float sup = uo * a2v, svp = vo * a2v;
#pragma unroll
    for (int m = 1; m < 64; m <<= 1) {
        sup += __shfl_xor(sup, m, 64);
        svp += __shfl_xor(svp, m, 64);
    }
    if (lane == 0) { su[n] = sup; sv[n] = svp; }
}

// histogram + free rank capture (atomicAdd's return value)
__global__ __launch_bounds__(256) void hist_kernel(
    const int* __restrict__ edge, int* __restrict__ count,
    int* __restrict__ rank, int E)
{
    const int i = blockIdx.x * 256 + threadIdx.x;
    if (i < E) rank[i] = atomicAdd(&count[edge[i]], 1);
}

__global__ __launch_bounds__(256) void scan_blocks_kernel(
    const int* __restrict__ count, int* __restrict__ base,
    int* __restrict__ blocksums, int N)
{
    __shared__ int lds[SCAN_BLOCK];
    const int b = blockIdx.x, t = threadIdx.x;
    const int idx0 = b * SCAN_TILE + t * SCAN_ITEMS;
    int vals[SCAN_ITEMS];
    int s = 0;
#pragma unroll
    for (int k = 0; k < SCAN_ITEMS; ++k) {
        const int idx = idx0 + k;
        const int c = (idx < N) ? count[idx] : 0;
        vals[k] = s; s += c;
    }
    lds[t] = s;
    __syncthreads();
    for (int off = 1; off < SCAN_BLOCK; off <<= 1) {
        const int xv = (t >= off) ? lds[t - off] : 0;
        __syncthreads();
        lds[t] += xv;
        __syncthreads();
    }
    const int excl = (t == 0) ? 0 : lds[t - 1];
#pragma unroll
    for (int k = 0; k < SCAN_ITEMS; ++k) {
        const int idx = idx0 + k;
        if (idx < N) base[idx] = excl + vals[k];
    }
    if (t == SCAN_BLOCK - 1) blocksums[b] = lds[t];
}

__global__ void scan_tops_kernel(int* __restrict__ blocksums, int nb)
{
    if (threadIdx.x == 0 && blockIdx.x == 0) {
        int s = 0;
        for (int i = 0; i < nb; ++i) { const int c = blocksums[i]; blocksums[i] = s; s += c; }
    }
}

// one THREAD per edge: scalar score + atomic-free CSR placement
__global__ __launch_bounds__(256) void edge_place_kernel(
    const int* __restrict__ edge, const int* __restrict__ etype,
    const float* __restrict__ G, int R,
    const float* __restrict__ su, const float* __restrict__ sv,
    const int* __restrict__ base, const int* __restrict__ blocksums,
    const int* __restrict__ rank,
    int4* __restrict__ csr, int E, int N)
{
    const int e = blockIdx.x * 256 + threadIdx.x;
    if (e >= E) return;
    const int s = edge[e];
    const int d = edge[(size_t)E + e];
    const int t = etype[e];
    if ((unsigned)s >= (unsigned)N || (unsigned)d >= (unsigned)N) return;

    const float g   = 0.5f * (G[s * R + t] + G[d * R + t]);
    const float raw = g * (su[s] + sv[d]);
    const float lr  = raw > 0.f ? raw : LRELU_ALPHA * raw;
    const float ee  = __expf(-lr);

    const int pos = base[s] + blocksums[s / SCAN_TILE] + rank[e];
    csr[pos] = make_int4(d, __float_as_int(ee * g), __float_as_int(ee), 0);
}

// one WAVE per node: wave-uniform broadcast CSR reads, x8-unrolled v-gathers
__global__ __launch_bounds__(256) void aggregate_kernel(
    const int* __restrict__ base, const int* __restrict__ blocksums,
    const int4* __restrict__ csr,
    const float* __restrict__ u, const float* __restrict__ v,
    float* __restrict__ out, int N, int E)
{
    const int wave = threadIdx.x >> 6;
    const int lane = threadIdx.x & 63;
    const int n = blockIdx.x * 4 + wave;
    if (n >= N) return;

    const int rs = base[n] + blocksums[n / SCAN_TILE];
    const int re = (n + 1 < N) ? (base[n + 1] + blocksums[(n + 1) / SCAN_TILE]) : E;

    float val = 0.f, sumw = 0.f, sumee = 0.f;

    int j = rs;
    for (; j + 8 <= re; j += 8) {
        int4 p[8];
#pragma unroll
        for (int k = 0; k < 8; ++k) p[k] = csr[j + k];   // wave-uniform broadcast
        float vv[8];
#pragma unroll
        for (int k = 0; k < 8; ++k) vv[k] = v[p[k].x * 64 + lane];
#pragma unroll
        for (int k = 0; k < 8; ++k) {
            const float w = __int_as_float(p[k].y);
            sumw  += w;
            sumee += __int_as_float(p[k].z);
            val   += w * vv[k];
        }
    }
    for (; j + 2 <= re; j += 2) {
        const int4 p0 = csr[j];
        const int4 p1 = csr[j + 1];
        const float v0 = v[p0.x * 64 + lane];
        const float v1 = v[p1.x * 64 + lane];
        const float w0 = __int_as_float(p0.y);
        const float w1 = __int_as_float(p1.y);
        sumw  += w0 + w1;
        sumee += __int_as_float(p0.z) + __int_as_float(p1.z);
        val   += w0 * v0 + w1 * v1;
    }
    for (; j < re; ++j) {
        const int4 p = csr[j];
        const float w = __int_as_float(p.y);
        sumw  += w;
        sumee += __int_as_float(p.z);
        val   += w * v[p.x * 64 + lane];
    }

    val += sumw * u[n * 64 + lane];
    const float r = (sumee == 0.f) ? 1e-12f : sumee;
    const float h = val / r;
    out[n * 64 + lane] = (h > 0.f) ? h : expm1f(h);
}

extern "C" void kernel_launch(void* const* d_in, const int* in_sizes, int n_in,
                              void* d_out, int out_size, void* d_ws, size_t ws_size,
                              hipStream_t stream)
{
    const float* x     = (const float*)d_in[0];
    const int*   edge  = (const int*)d_in[1];
    // d_in[2] = edge_embed: unused by the reference computation
    const int*   etype = (const int*)d_in[3];
    const float* G     = (const float*)d_in[4];
    const float* a     = (const float*)d_in[5];
    const float* a2    = (const float*)d_in[6];

    const int N = in_sizes[0] / 64;
    const int E = in_sizes[1] / 2;
    const int R = in_sizes[4] / N;

    float* out = (float*)d_out;

    // workspace layout (~42 MB):
    // u[N*64] | v[N*64] | su[N] | sv[N] | count[N] | base[N] |
    // blocksums[nsb] | rank[E] | csr[E] (int4)
    float* u      = (float*)d_ws;
    float* v      = u + (size_t)N * 64;
    float* su     = v + (size_t)N * 64;
    float* sv     = su + N;
    int*   count  = (int*)(sv + N);
    int*   base   = count + N;
    const int nsb = (N + SCAN_TILE - 1) / SCAN_TILE;
    int*   blocksums = base + N;
    int*   rank   = blocksums + ((nsb + 63) & ~63);
    int*   tail   = rank + E;
    int4*  csr    = (int4*)((((uintptr_t)tail) + 15) & ~(uintptr_t)15);

    node_transform_kernel<<<dim3((N + 3) / 4), dim3(256), 0, stream>>>(
        x, a, a2, u, v, su, sv, count, N);
    hist_kernel<<<dim3((E + 255) / 256), dim3(256), 0, stream>>>(edge, count, rank, E);
    scan_blocks_kernel<<<dim3(nsb), dim3(SCAN_BLOCK), 0, stream>>>(count, base, blocksums, N);
    scan_tops_kernel<<<dim3(1), dim3(64), 0, stream>>>(blocksums, nsb);
    edge_place_kernel<<<dim3((E + 255) / 256), dim3(256), 0, stream>>>(
        edge, etype, G, R, su, sv, base, blocksums, rank, csr, E, N);
    aggregate_kernel<<<dim3((N + 3) / 4), dim3(256), 0, stream>>>(
        base, blocksums, csr, u, v, out, N, E);
}

// Round 9
// 174.346 us; speedup vs baseline: 1.0583x; 1.0583x over previous
//
#include <hip/hip_runtime.h>
#include <hip/hip_bf16.h>

// GrCNet attention layer — CSR gather formulation.
//   u[n] = W1 x[n], v[n] = W2 x[n]   (a = [W1 | W2], [64,128] row-major)
//   su[n] = u[n].a2, sv[n] = v[n].a2   (f32, exact)
//   edge e: g = 0.5*(G[s,t]+G[d,t]); ee = exp(-lrelu(g*(su[s]+sv[d]))); w = ee*g
//   CSR-by-src stores packed int4 (d, w, ee, 0)
//   h[n] = elu( ((Σw)·u[n] + Σ w·v[d]) / Σee )
//
// Round 9: (1) aggregate reverted to R7 coalesced-CSR + shfl (R8's broadcast
// form issued 8x more VMEM instructions — measured +4.5us). (2) u/v stored as
// BF16: halves the dominant 205MB v-gather traffic + u reads + node writes.
// All attention-weight math (su/sv/g/ee/w) stays f32. (3) hist vectorized x4.

#define LRELU_ALPHA 0.2f
#define SCAN_BLOCK 256
#define SCAN_ITEMS 8
#define SCAN_TILE (SCAN_BLOCK * SCAN_ITEMS)  // 2048

__global__ __launch_bounds__(256) void node_transform_kernel(
    const float* __restrict__ x, const float* __restrict__ a,
    const float* __restrict__ a2,
    __hip_bfloat16* __restrict__ u_bf, __hip_bfloat16* __restrict__ v_bf,
    float* __restrict__ su, float* __restrict__ sv,
    int* __restrict__ count, int N)
{
    __shared__ float a_lds[64][129];
    for (int idx = threadIdx.x; idx < 64 * 128; idx += 256)
        a_lds[idx >> 7][idx & 127] = a[idx];
    __syncthreads();

    const int wave = threadIdx.x >> 6;
    const int lane = threadIdx.x & 63;
    const int n = blockIdx.x * 4 + wave;
    if (n >= N) return;

    if (lane == 0) count[n] = 0;

    const float a2v = a2[lane];
    const float* xr = x + (size_t)n * 64;
    float uo = 0.f, vo = 0.f;
#pragma unroll 8
    for (int i = 0; i < 64; ++i) {
        const float xi = xr[i];
        uo += xi * a_lds[lane][i];
        vo += xi * a_lds[lane][64 + i];
    }
    u_bf[(size_t)n * 64 + lane] = __float2bfloat16(uo);
    v_bf[(size_t)n * 64 + lane] = __float2bfloat16(vo);

    float sup = uo * a2v, svp = vo * a2v;   // f32 score path, exact
#pragma unroll
    for (int m = 1; m < 64; m <<= 1) {
        sup += __shfl_xor(sup, m, 64);
        svp += __shfl_xor(svp, m, 64);
    }
    if (lane == 0) { su[n] = sup; sv[n] = svp; }
}

// histogram + free rank capture, 4 edges per thread (int4 I/O)
__global__ __launch_bounds__(256) void hist_kernel(
    const int* __restrict__ edge, int* __restrict__ count,
    int* __restrict__ rank, int E)
{
    const int i4 = (blockIdx.x * 256 + threadIdx.x) * 4;
    if (i4 + 3 < E) {
        const int4 s4 = *(const int4*)(edge + i4);
        int4 r4;
        r4.x = atomicAdd(&count[s4.x], 1);
        r4.y = atomicAdd(&count[s4.y], 1);
        r4.z = atomicAdd(&count[s4.z], 1);
        r4.w = atomicAdd(&count[s4.w], 1);
        *(int4*)(rank + i4) = r4;
    } else {
        for (int i = i4; i < E; ++i)
            rank[i] = atomicAdd(&count[edge[i]], 1);
    }
}

__global__ __launch_bounds__(256) void scan_blocks_kernel(
    const int* __restrict__ count, int* __restrict__ base,
    int* __restrict__ blocksums, int N)
{
    __shared__ int lds[SCAN_BLOCK];
    const int b = blockIdx.x, t = threadIdx.x;
    const int idx0 = b * SCAN_TILE + t * SCAN_ITEMS;
    int vals[SCAN_ITEMS];
    int s = 0;
#pragma unroll
    for (int k = 0; k < SCAN_ITEMS; ++k) {
        const int idx = idx0 + k;
        const int c = (idx < N) ? count[idx] : 0;
        vals[k] = s; s += c;
    }
    lds[t] = s;
    __syncthreads();
    for (int off = 1; off < SCAN_BLOCK; off <<= 1) {
        const int xv = (t >= off) ? lds[t - off] : 0;
        __syncthreads();
        lds[t] += xv;
        __syncthreads();
    }
    const int excl = (t == 0) ? 0 : lds[t - 1];
#pragma unroll
    for (int k = 0; k < SCAN_ITEMS; ++k) {
        const int idx = idx0 + k;
        if (idx < N) base[idx] = excl + vals[k];
    }
    if (t == SCAN_BLOCK - 1) blocksums[b] = lds[t];
}

__global__ void scan_tops_kernel(int* __restrict__ blocksums, int nb)
{
    if (threadIdx.x == 0 && blockIdx.x == 0) {
        int s = 0;
        for (int i = 0; i < nb; ++i) { const int c = blocksums[i]; blocksums[i] = s; s += c; }
    }
}

// one THREAD per edge: scalar score + atomic-free CSR placement
__global__ __launch_bounds__(256) void edge_place_kernel(
    const int* __restrict__ edge, const int* __restrict__ etype,
    const float* __restrict__ G, int R,
    const float* __restrict__ su, const float* __restrict__ sv,
    const int* __restrict__ base, const int* __restrict__ blocksums,
    const int* __restrict__ rank,
    int4* __restrict__ csr, int E, int N)
{
    const int e = blockIdx.x * 256 + threadIdx.x;
    if (e >= E) return;
    const int s = edge[e];
    const int d = edge[(size_t)E + e];
    const int t = etype[e];
    if ((unsigned)s >= (unsigned)N || (unsigned)d >= (unsigned)N) return;

    const float g   = 0.5f * (G[s * R + t] + G[d * R + t]);
    const float raw = g * (su[s] + sv[d]);
    const float lr  = raw > 0.f ? raw : LRELU_ALPHA * raw;
    const float ee  = __expf(-lr);

    const int pos = base[s] + blocksums[s / SCAN_TILE] + rank[e];
    csr[pos] = make_int4(d, __float_as_int(ee * g), __float_as_int(ee), 0);
}

// one WAVE per node: coalesced CSR + shfl broadcast, bf16 v/u, fused finalize
__global__ __launch_bounds__(256) void aggregate_kernel(
    const int* __restrict__ base, const int* __restrict__ blocksums,
    const int4* __restrict__ csr,
    const __hip_bfloat16* __restrict__ u_bf,
    const __hip_bfloat16* __restrict__ v_bf,
    float* __restrict__ out, int N, int E)
{
    const int wave = threadIdx.x >> 6;
    const int lane = threadIdx.x & 63;
    const int n = blockIdx.x * 4 + wave;
    if (n >= N) return;

    const int rs = base[n] + blocksums[n / SCAN_TILE];
    const int re = (n + 1 < N) ? (base[n + 1] + blocksums[(n + 1) / SCAN_TILE]) : E;

    float val = 0.f, sumw_p = 0.f, sumee_p = 0.f;

    for (int i = rs; i < re; i += 64) {
        const int m = min(64, re - i);
        int dl = 0; float wl = 0.f, eel = 0.f;
        if (lane < m) {
            const int4 p = csr[i + lane];
            dl  = p.x;
            wl  = __int_as_float(p.y);
            eel = __int_as_float(p.z);
        }
        sumw_p  += wl;
        sumee_p += eel;
        int j = 0;
        for (; j + 8 <= m; j += 8) {
            int   dd[8]; float ww[8], vv[8];
#pragma unroll
            for (int k = 0; k < 8; ++k) {
                dd[k] = __shfl(dl, j + k, 64);
                ww[k] = __shfl(wl, j + k, 64);
            }
#pragma unroll
            for (int k = 0; k < 8; ++k)
                vv[k] = __bfloat162float(v_bf[(size_t)dd[k] * 64 + lane]);
#pragma unroll
            for (int k = 0; k < 8; ++k) val += ww[k] * vv[k];
        }
        for (; j + 4 <= m; j += 4) {
            int   dd[4]; float ww[4], vv[4];
#pragma unroll
            for (int k = 0; k < 4; ++k) {
                dd[k] = __shfl(dl, j + k, 64);
                ww[k] = __shfl(wl, j + k, 64);
            }
#pragma unroll
            for (int k = 0; k < 4; ++k)
                vv[k] = __bfloat162float(v_bf[(size_t)dd[k] * 64 + lane]);
#pragma unroll
            for (int k = 0; k < 4; ++k) val += ww[k] * vv[k];
        }
        for (; j < m; ++j) {
            const int   dj = __shfl(dl, j, 64);
            const float wj = __shfl(wl, j, 64);
            val += wj * __bfloat162float(v_bf[(size_t)dj * 64 + lane]);
        }
    }

    float sumw = sumw_p, sumee = sumee_p;
#pragma unroll
    for (int m2 = 1; m2 < 64; m2 <<= 1) {
        sumw  += __shfl_xor(sumw,  m2, 64);
        sumee += __shfl_xor(sumee, m2, 64);
    }

    val += sumw * __bfloat162float(u_bf[(size_t)n * 64 + lane]);
    const float r = (sumee == 0.f) ? 1e-12f : sumee;
    const float h = val / r;
    out[(size_t)n * 64 + lane] = (h > 0.f) ? h : expm1f(h);
}

extern "C" void kernel_launch(void* const* d_in, const int* in_sizes, int n_in,
                              void* d_out, int out_size, void* d_ws, size_t ws_size,
                              hipStream_t stream)
{
    const float* x     = (const float*)d_in[0];
    const int*   edge  = (const int*)d_in[1];
    // d_in[2] = edge_embed: unused by the reference computation
    const int*   etype = (const int*)d_in[3];
    const float* G     = (const float*)d_in[4];
    const float* a     = (const float*)d_in[5];
    const float* a2    = (const float*)d_in[6];

    const int N = in_sizes[0] / 64;
    const int E = in_sizes[1] / 2;
    const int R = in_sizes[4] / N;

    float* out = (float*)d_out;

    // workspace layout (~29 MB):
    // u_bf[N*64] | v_bf[N*64] (bf16) | su[N] | sv[N] | count[N] | base[N] |
    // blocksums[nsb] | rank[E] | csr[E] (int4)
    __hip_bfloat16* u_bf = (__hip_bfloat16*)d_ws;
    __hip_bfloat16* v_bf = u_bf + (size_t)N * 64;
    float* su     = (float*)(v_bf + (size_t)N * 64);
    float* sv     = su + N;
    int*   count  = (int*)(sv + N);
    int*   base   = count + N;
    const int nsb = (N + SCAN_TILE - 1) / SCAN_TILE;
    int*   blocksums = base + N;
    int*   rank   = blocksums + ((nsb + 63) & ~63);
    int*   tail   = rank + E;
    int4*  csr    = (int4*)((((uintptr_t)tail) + 15) & ~(uintptr_t)15);

    node_transform_kernel<<<dim3((N + 3) / 4), dim3(256), 0, stream>>>(
        x, a, a2, u_bf, v_bf, su, sv, count, N);
    hist_kernel<<<dim3(((E + 3) / 4 + 255) / 256), dim3(256), 0, stream>>>(
        edge, count, rank, E);
    scan_blocks_kernel<<<dim3(nsb), dim3(SCAN_BLOCK), 0, stream>>>(count, base, blocksums, N);
    scan_tops_kernel<<<dim3(1), dim3(64), 0, stream>>>(blocksums, nsb);
    edge_place_kernel<<<dim3((E + 255) / 256), dim3(256), 0, stream>>>(
        edge, etype, G, R, su, sv, base, blocksums, rank, csr, E, N);
    aggregate_kernel<<<dim3((N + 3) / 4), dim3(256), 0, stream>>>(
        base, blocksums, csr, u_bf, v_bf, out, N, E);
}

// Round 10
// 173.806 us; speedup vs baseline: 1.0616x; 1.0031x over previous
//
#include <hip/hip_runtime.h>
#include <hip/hip_bf16.h>

// GrCNet attention layer — CSR gather formulation.
//   u[n] = W1 x[n], v[n] = W2 x[n]   (a = [W1 | W2], [64,128] row-major)
//   su[n] = u[n].a2, sv[n] = v[n].a2   (f32, exact)
//   edge e: g = 0.5*(G[s,t]+G[d,t]); ee = exp(-lrelu(g*(su[s]+sv[d]))); w = ee*g
//   CSR-by-src stores packed int4 (d, w, ee, 0)
//   h[n] = elu( ((Σw)·u[n] + Σ w·v[d]) / Σee )
//
// Round 10: aggregate restructured to quad-channel lanes — lane owns channels
// 4c..4c+3 (c=lane&15, uint2 = 4xbf16) and entry slot r=lane>>4. One gather
// instruction fetches FOUR v-rows (64 lanes x 8B) instead of one (64 x 2B):
// 4x fewer gather issues, 4x fewer bpermutes per entry, same traffic/precision.

#define LRELU_ALPHA 0.2f
#define SCAN_BLOCK 256
#define SCAN_ITEMS 8
#define SCAN_TILE (SCAN_BLOCK * SCAN_ITEMS)  // 2048

__device__ __forceinline__ float bflo(unsigned int q) {
    return __int_as_float((int)(q << 16));
}
__device__ __forceinline__ float bfhi(unsigned int q) {
    return __int_as_float((int)(q & 0xffff0000u));
}

__global__ __launch_bounds__(256) void node_transform_kernel(
    const float* __restrict__ x, const float* __restrict__ a,
    const float* __restrict__ a2,
    __hip_bfloat16* __restrict__ u_bf, __hip_bfloat16* __restrict__ v_bf,
    float* __restrict__ su, float* __restrict__ sv,
    int* __restrict__ count, int N)
{
    __shared__ float a_lds[64][129];
    for (int idx = threadIdx.x; idx < 64 * 128; idx += 256)
        a_lds[idx >> 7][idx & 127] = a[idx];
    __syncthreads();

    const int wave = threadIdx.x >> 6;
    const int lane = threadIdx.x & 63;
    const int n = blockIdx.x * 4 + wave;
    if (n >= N) return;

    if (lane == 0) count[n] = 0;

    const float a2v = a2[lane];
    const float* xr = x + (size_t)n * 64;
    float uo = 0.f, vo = 0.f;
#pragma unroll 8
    for (int i = 0; i < 64; ++i) {
        const float xi = xr[i];
        uo += xi * a_lds[lane][i];
        vo += xi * a_lds[lane][64 + i];
    }
    u_bf[(size_t)n * 64 + lane] = __float2bfloat16(uo);
    v_bf[(size_t)n * 64 + lane] = __float2bfloat16(vo);

    float sup = uo * a2v, svp = vo * a2v;   // f32 score path, exact
#pragma unroll
    for (int m = 1; m < 64; m <<= 1) {
        sup += __shfl_xor(sup, m, 64);
        svp += __shfl_xor(svp, m, 64);
    }
    if (lane == 0) { su[n] = sup; sv[n] = svp; }
}

// histogram + free rank capture, 4 edges per thread (int4 I/O)
__global__ __launch_bounds__(256) void hist_kernel(
    const int* __restrict__ edge, int* __restrict__ count,
    int* __restrict__ rank, int E)
{
    const int i4 = (blockIdx.x * 256 + threadIdx.x) * 4;
    if (i4 + 3 < E) {
        const int4 s4 = *(const int4*)(edge + i4);
        int4 r4;
        r4.x = atomicAdd(&count[s4.x], 1);
        r4.y = atomicAdd(&count[s4.y], 1);
        r4.z = atomicAdd(&count[s4.z], 1);
        r4.w = atomicAdd(&count[s4.w], 1);
        *(int4*)(rank + i4) = r4;
    } else {
        for (int i = i4; i < E; ++i)
            rank[i] = atomicAdd(&count[edge[i]], 1);
    }
}

__global__ __launch_bounds__(256) void scan_blocks_kernel(
    const int* __restrict__ count, int* __restrict__ base,
    int* __restrict__ blocksums, int N)
{
    __shared__ int lds[SCAN_BLOCK];
    const int b = blockIdx.x, t = threadIdx.x;
    const int idx0 = b * SCAN_TILE + t * SCAN_ITEMS;
    int vals[SCAN_ITEMS];
    int s = 0;
#pragma unroll
    for (int k = 0; k < SCAN_ITEMS; ++k) {
        const int idx = idx0 + k;
        const int c = (idx < N) ? count[idx] : 0;
        vals[k] = s; s += c;
    }
    lds[t] = s;
    __syncthreads();
    for (int off = 1; off < SCAN_BLOCK; off <<= 1) {
        const int xv = (t >= off) ? lds[t - off] : 0;
        __syncthreads();
        lds[t] += xv;
        __syncthreads();
    }
    const int excl = (t == 0) ? 0 : lds[t - 1];
#pragma unroll
    for (int k = 0; k < SCAN_ITEMS; ++k) {
        const int idx = idx0 + k;
        if (idx < N) base[idx] = excl + vals[k];
    }
    if (t == SCAN_BLOCK - 1) blocksums[b] = lds[t];
}

__global__ void scan_tops_kernel(int* __restrict__ blocksums, int nb)
{
    if (threadIdx.x == 0 && blockIdx.x == 0) {
        int s = 0;
        for (int i = 0; i < nb; ++i) { const int c = blocksums[i]; blocksums[i] = s; s += c; }
    }
}

// one THREAD per edge: scalar score + atomic-free CSR placement
__global__ __launch_bounds__(256) void edge_place_kernel(
    const int* __restrict__ edge, const int* __restrict__ etype,
    const float* __restrict__ G, int R,
    const float* __restrict__ su, const float* __restrict__ sv,
    const int* __restrict__ base, const int* __restrict__ blocksums,
    const int* __restrict__ rank,
    int4* __restrict__ csr, int E, int N)
{
    const int e = blockIdx.x * 256 + threadIdx.x;
    if (e >= E) return;
    const int s = edge[e];
    const int d = edge[(size_t)E + e];
    const int t = etype[e];
    if ((unsigned)s >= (unsigned)N || (unsigned)d >= (unsigned)N) return;

    const float g   = 0.5f * (G[s * R + t] + G[d * R + t]);
    const float raw = g * (su[s] + sv[d]);
    const float lr  = raw > 0.f ? raw : LRELU_ALPHA * raw;
    const float ee  = __expf(-lr);

    const int pos = base[s] + blocksums[s / SCAN_TILE] + rank[e];
    csr[pos] = make_int4(d, __float_as_int(ee * g), __float_as_int(ee), 0);
}

// one WAVE per node: quad-channel lanes — 4 v-rows per gather instruction.
// lane = (r:2)(c:4): channel quad c (channels 4c..4c+3), entry slot r.
__global__ __launch_bounds__(256) void aggregate_kernel(
    const int* __restrict__ base, const int* __restrict__ blocksums,
    const int4* __restrict__ csr,
    const uint2* __restrict__ u_bf4,   // node rows as 16 x uint2 (4 bf16 each)
    const uint2* __restrict__ v_bf4,
    float* __restrict__ out, int N, int E)
{
    const int wave = threadIdx.x >> 6;
    const int lane = threadIdx.x & 63;
    const int n = blockIdx.x * 4 + wave;
    if (n >= N) return;

    const int rs = base[n] + blocksums[n / SCAN_TILE];
    const int re = (n + 1 < N) ? (base[n + 1] + blocksums[(n + 1) / SCAN_TILE]) : E;

    const int c = lane & 15;   // channel quad
    const int r = lane >> 4;   // entry slot (0..3)

    float v0 = 0.f, v1 = 0.f, v2 = 0.f, v3 = 0.f;
    float sumw_p = 0.f, sumee_p = 0.f;

    for (int i = rs; i < re; i += 64) {
        const int m = min(64, re - i);
        int dl = 0; float wl = 0.f, eel = 0.f;
        if (lane < m) {
            const int4 p = csr[i + lane];
            dl  = p.x;
            wl  = __int_as_float(p.y);
            eel = __int_as_float(p.z);
        }
        sumw_p  += wl;
        sumee_p += eel;
        // 8 entries per iteration: two 4-row wide gathers. Slots beyond m are
        // safe: wl==0 there, dl==0 -> harmless row-0 gather, zero contribution.
        for (int j = 0; j < m; j += 8) {
            const int   jA = j + r;
            const int   jB = j + 4 + r;
            const int   dA = __shfl(dl, jA, 64);
            const float wA = __shfl(wl, jA, 64);
            const int   dB = __shfl(dl, jB, 64);
            const float wB = __shfl(wl, jB, 64);
            const uint2 qa = v_bf4[(size_t)dA * 16 + c];
            const uint2 qb = v_bf4[(size_t)dB * 16 + c];
            v0 += wA * bflo(qa.x);
            v1 += wA * bfhi(qa.x);
            v2 += wA * bflo(qa.y);
            v3 += wA * bfhi(qa.y);
            v0 += wB * bflo(qb.x);
            v1 += wB * bfhi(qb.x);
            v2 += wB * bflo(qb.y);
            v3 += wB * bfhi(qb.y);
        }
    }

    float sumw = sumw_p, sumee = sumee_p;
#pragma unroll
    for (int m2 = 1; m2 < 64; m2 <<= 1) {
        sumw  += __shfl_xor(sumw,  m2, 64);
        sumee += __shfl_xor(sumee, m2, 64);
    }

    // combine the 4 entry-slot groups (r) per channel quad
    v0 += __shfl_xor(v0, 16, 64);  v0 += __shfl_xor(v0, 32, 64);
    v1 += __shfl_xor(v1, 16, 64);  v1 += __shfl_xor(v1, 32, 64);
    v2 += __shfl_xor(v2, 16, 64);  v2 += __shfl_xor(v2, 32, 64);
    v3 += __shfl_xor(v3, 16, 64);  v3 += __shfl_xor(v3, 32, 64);

    const uint2 qu = u_bf4[(size_t)n * 16 + c];
    v0 += sumw * bflo(qu.x);
    v1 += sumw * bfhi(qu.x);
    v2 += sumw * bflo(qu.y);
    v3 += sumw * bfhi(qu.y);

    const float rden = (sumee == 0.f) ? 1e-12f : sumee;
    const float h0 = v0 / rden, h1 = v1 / rden, h2 = v2 / rden, h3 = v3 / rden;
    if (lane < 16) {
        float4 o;
        o.x = (h0 > 0.f) ? h0 : expm1f(h0);
        o.y = (h1 > 0.f) ? h1 : expm1f(h1);
        o.z = (h2 > 0.f) ? h2 : expm1f(h2);
        o.w = (h3 > 0.f) ? h3 : expm1f(h3);
        ((float4*)out)[(size_t)n * 16 + c] = o;
    }
}

extern "C" void kernel_launch(void* const* d_in, const int* in_sizes, int n_in,
                              void* d_out, int out_size, void* d_ws, size_t ws_size,
                              hipStream_t stream)
{
    const float* x     = (const float*)d_in[0];
    const int*   edge  = (const int*)d_in[1];
    // d_in[2] = edge_embed: unused by the reference computation
    const int*   etype = (const int*)d_in[3];
    const float* G     = (const float*)d_in[4];
    const float* a     = (const float*)d_in[5];
    const float* a2    = (const float*)d_in[6];

    const int N = in_sizes[0] / 64;
    const int E = in_sizes[1] / 2;
    const int R = in_sizes[4] / N;

    float* out = (float*)d_out;

    // workspace layout (~29 MB):
    // u_bf[N*64] | v_bf[N*64] (bf16) | su[N] | sv[N] | count[N] | base[N] |
    // blocksums[nsb] | rank[E] | csr[E] (int4)
    __hip_bfloat16* u_bf = (__hip_bfloat16*)d_ws;
    __hip_bfloat16* v_bf = u_bf + (size_t)N * 64;
    float* su     = (float*)(v_bf + (size_t)N * 64);
    float* sv     = su + N;
    int*   count  = (int*)(sv + N);
    int*   base   = count + N;
    const int nsb = (N + SCAN_TILE - 1) / SCAN_TILE;
    int*   blocksums = base + N;
    int*   rank   = blocksums + ((nsb + 63) & ~63);
    int*   tail   = rank + E;
    int4*  csr    = (int4*)((((uintptr_t)tail) + 15) & ~(uintptr_t)15);

    node_transform_kernel<<<dim3((N + 3) / 4), dim3(256), 0, stream>>>(
        x, a, a2, u_bf, v_bf, su, sv, count, N);
    hist_kernel<<<dim3(((E + 3) / 4 + 255) / 256), dim3(256), 0, stream>>>(
        edge, count, rank, E);
    scan_blocks_kernel<<<dim3(nsb), dim3(SCAN_BLOCK), 0, stream>>>(count, base, blocksums, N);
    scan_tops_kernel<<<dim3(1), dim3(64), 0, stream>>>(blocksums, nsb);
    edge_place_kernel<<<dim3((E + 255) / 256), dim3(256), 0, stream>>>(
        edge, etype, G, R, su, sv, base, blocksums, rank, csr, E, N);
    aggregate_kernel<<<dim3((N + 3) / 4), dim3(256), 0, stream>>>(
        base, blocksums, csr, (const uint2*)u_bf, (const uint2*)v_bf, out, N, E);
}

// Round 11
// 155.453 us; speedup vs baseline: 1.1869x; 1.1181x over previous
//
#include <hip/hip_runtime.h>
#include <hip/hip_bf16.h>

// GrCNet attention layer — CSR gather formulation, score fused into aggregate.
//   u[n] = W1 x[n], v[n] = W2 x[n]   (a = [W1 | W2], [64,128] row-major)
//   su[n] = u[n].a2, sv[n] = v[n].a2   (f32, exact)
//   edge e: g = 0.5*(G[s,t]+G[d,t]); ee = exp(-lrelu(g*(su[s]+sv[d]))); w = ee*g
//   CSR-by-src stores ONE uint32 per edge: (d<<8)|t   (requires R<=256, N<2^24)
//   h[n] = elu( ((Σw)·u[n] + Σ w·v[d]) / Σee )
//
// Round 11: score computation moved from edge_place (edge order: G[s,t] and
// G[d,t] BOTH random) into aggregate (node order: G[n,t] is the node's own
// 800B row -> L1; su[n] uniform). CSR shrinks 16B -> 4B (w/ee recomputed).
// edge_place is now pure placement: no float math, 4B scatter.

#define LRELU_ALPHA 0.2f
#define SCAN_BLOCK 256
#define SCAN_ITEMS 8
#define SCAN_TILE (SCAN_BLOCK * SCAN_ITEMS)  // 2048

__device__ __forceinline__ float bflo(unsigned int q) {
    return __int_as_float((int)(q << 16));
}
__device__ __forceinline__ float bfhi(unsigned int q) {
    return __int_as_float((int)(q & 0xffff0000u));
}

__global__ __launch_bounds__(256) void node_transform_kernel(
    const float* __restrict__ x, const float* __restrict__ a,
    const float* __restrict__ a2,
    __hip_bfloat16* __restrict__ u_bf, __hip_bfloat16* __restrict__ v_bf,
    float* __restrict__ su, float* __restrict__ sv,
    int* __restrict__ count, int N)
{
    __shared__ float a_lds[64][129];
    for (int idx = threadIdx.x; idx < 64 * 128; idx += 256)
        a_lds[idx >> 7][idx & 127] = a[idx];
    __syncthreads();

    const int wave = threadIdx.x >> 6;
    const int lane = threadIdx.x & 63;
    const int n = blockIdx.x * 4 + wave;
    if (n >= N) return;

    if (lane == 0) count[n] = 0;

    const float a2v = a2[lane];
    const float* xr = x + (size_t)n * 64;
    float uo = 0.f, vo = 0.f;
#pragma unroll 8
    for (int i = 0; i < 64; ++i) {
        const float xi = xr[i];
        uo += xi * a_lds[lane][i];
        vo += xi * a_lds[lane][64 + i];
    }
    u_bf[(size_t)n * 64 + lane] = __float2bfloat16(uo);
    v_bf[(size_t)n * 64 + lane] = __float2bfloat16(vo);

    float sup = uo * a2v, svp = vo * a2v;   // f32 score path, exact
#pragma unroll
    for (int m = 1; m < 64; m <<= 1) {
        sup += __shfl_xor(sup, m, 64);
        svp += __shfl_xor(svp, m, 64);
    }
    if (lane == 0) { su[n] = sup; sv[n] = svp; }
}

// histogram + free rank capture, 4 edges per thread (int4 I/O)
__global__ __launch_bounds__(256) void hist_kernel(
    const int* __restrict__ edge, int* __restrict__ count,
    int* __restrict__ rank, int E)
{
    const int i4 = (blockIdx.x * 256 + threadIdx.x) * 4;
    if (i4 + 3 < E) {
        const int4 s4 = *(const int4*)(edge + i4);
        int4 r4;
        r4.x = atomicAdd(&count[s4.x], 1);
        r4.y = atomicAdd(&count[s4.y], 1);
        r4.z = atomicAdd(&count[s4.z], 1);
        r4.w = atomicAdd(&count[s4.w], 1);
        *(int4*)(rank + i4) = r4;
    } else {
        for (int i = i4; i < E; ++i)
            rank[i] = atomicAdd(&count[edge[i]], 1);
    }
}

__global__ __launch_bounds__(256) void scan_blocks_kernel(
    const int* __restrict__ count, int* __restrict__ base,
    int* __restrict__ blocksums, int N)
{
    __shared__ int lds[SCAN_BLOCK];
    const int b = blockIdx.x, t = threadIdx.x;
    const int idx0 = b * SCAN_TILE + t * SCAN_ITEMS;
    int vals[SCAN_ITEMS];
    int s = 0;
#pragma unroll
    for (int k = 0; k < SCAN_ITEMS; ++k) {
        const int idx = idx0 + k;
        const int c = (idx < N) ? count[idx] : 0;
        vals[k] = s; s += c;
    }
    lds[t] = s;
    __syncthreads();
    for (int off = 1; off < SCAN_BLOCK; off <<= 1) {
        const int xv = (t >= off) ? lds[t - off] : 0;
        __syncthreads();
        lds[t] += xv;
        __syncthreads();
    }
    const int excl = (t == 0) ? 0 : lds[t - 1];
#pragma unroll
    for (int k = 0; k < SCAN_ITEMS; ++k) {
        const int idx = idx0 + k;
        if (idx < N) base[idx] = excl + vals[k];
    }
    if (t == SCAN_BLOCK - 1) blocksums[b] = lds[t];
}

__global__ void scan_tops_kernel(int* __restrict__ blocksums, int nb)
{
    if (threadIdx.x == 0 && blockIdx.x == 0) {
        int s = 0;
        for (int i = 0; i < nb; ++i) { const int c = blocksums[i]; blocksums[i] = s; s += c; }
    }
}

// one THREAD per edge: pure CSR placement, no float math, 4B scatter
__global__ __launch_bounds__(256) void edge_place_kernel(
    const int* __restrict__ edge, const int* __restrict__ etype,
    const int* __restrict__ base, const int* __restrict__ blocksums,
    const int* __restrict__ rank,
    unsigned int* __restrict__ csr, int E, int N, int R)
{
    const int e = blockIdx.x * 256 + threadIdx.x;
    if (e >= E) return;
    const int s = edge[e];
    const int d = edge[(size_t)E + e];
    const int t = etype[e];
    if ((unsigned)s >= (unsigned)N || (unsigned)d >= (unsigned)N ||
        (unsigned)t >= (unsigned)R) return;

    const int pos = base[s] + blocksums[s / SCAN_TILE] + rank[e];
    csr[pos] = ((unsigned)d << 8) | (unsigned)t;
}

// one WAVE per node: fused score + quad-channel v-gathers.
// lane = (r:2)(c:4): channel quad c (channels 4c..4c+3), entry slot r.
__global__ __launch_bounds__(256) void aggregate_kernel(
    const int* __restrict__ base, const int* __restrict__ blocksums,
    const unsigned int* __restrict__ csr,
    const uint2* __restrict__ u_bf4,   // node rows as 16 x uint2 (4 bf16 each)
    const uint2* __restrict__ v_bf4,
    const float* __restrict__ su, const float* __restrict__ sv,
    const float* __restrict__ G, int R,
    float* __restrict__ out, int N, int E)
{
    const int wave = threadIdx.x >> 6;
    const int lane = threadIdx.x & 63;
    const int n = blockIdx.x * 4 + wave;
    if (n >= N) return;

    const int rs = base[n] + blocksums[n / SCAN_TILE];
    const int re = (n + 1 < N) ? (base[n + 1] + blocksums[(n + 1) / SCAN_TILE]) : E;

    const int c = lane & 15;   // channel quad
    const int r = lane >> 4;   // entry slot (0..3)

    const float su_n = su[n];
    const float* __restrict__ Gn = G + (size_t)n * R;   // node's own row: L1

    float v0 = 0.f, v1 = 0.f, v2 = 0.f, v3 = 0.f;
    float sumw_p = 0.f, sumee_p = 0.f;

    for (int i = rs; i < re; i += 64) {
        const int m = min(64, re - i);
        int dl = 0; float wl = 0.f, eel = 0.f;
        if (lane < m) {
            const unsigned p = csr[i + lane];
            const int d = (int)(p >> 8);
            const int t = (int)(p & 255u);
            const float g   = 0.5f * (Gn[t] + G[(size_t)d * R + t]);
            const float raw = g * (su_n + sv[d]);
            const float lr  = raw > 0.f ? raw : LRELU_ALPHA * raw;
            const float ee  = __expf(-lr);
            dl  = d;
            eel = ee;
            wl  = ee * g;
        }
        sumw_p  += wl;
        sumee_p += eel;
        // 8 entries per iteration: two 4-row wide gathers. Slots beyond m are
        // safe: wl==0 there, dl==0 -> harmless row-0 gather, zero contribution.
        for (int j = 0; j < m; j += 8) {
            const int   jA = j + r;
            const int   jB = j + 4 + r;
            const int   dA = __shfl(dl, jA, 64);
            const float wA = __shfl(wl, jA, 64);
            const int   dB = __shfl(dl, jB, 64);
            const float wB = __shfl(wl, jB, 64);
            const uint2 qa = v_bf4[(size_t)dA * 16 + c];
            const uint2 qb = v_bf4[(size_t)dB * 16 + c];
            v0 += wA * bflo(qa.x);
            v1 += wA * bfhi(qa.x);
            v2 += wA * bflo(qa.y);
            v3 += wA * bfhi(qa.y);
            v0 += wB * bflo(qb.x);
            v1 += wB * bfhi(qb.x);
            v2 += wB * bflo(qb.y);
            v3 += wB * bfhi(qb.y);
        }
    }

    float sumw = sumw_p, sumee = sumee_p;
#pragma unroll
    for (int m2 = 1; m2 < 64; m2 <<= 1) {
        sumw  += __shfl_xor(sumw,  m2, 64);
        sumee += __shfl_xor(sumee, m2, 64);
    }

    // combine the 4 entry-slot groups (r) per channel quad
    v0 += __shfl_xor(v0, 16, 64);  v0 += __shfl_xor(v0, 32, 64);
    v1 += __shfl_xor(v1, 16, 64);  v1 += __shfl_xor(v1, 32, 64);
    v2 += __shfl_xor(v2, 16, 64);  v2 += __shfl_xor(v2, 32, 64);
    v3 += __shfl_xor(v3, 16, 64);  v3 += __shfl_xor(v3, 32, 64);

    const uint2 qu = u_bf4[(size_t)n * 16 + c];
    v0 += sumw * bflo(qu.x);
    v1 += sumw * bfhi(qu.x);
    v2 += sumw * bflo(qu.y);
    v3 += sumw * bfhi(qu.y);

    const float rden = (sumee == 0.f) ? 1e-12f : sumee;
    const float h0 = v0 / rden, h1 = v1 / rden, h2 = v2 / rden, h3 = v3 / rden;
    if (lane < 16) {
        float4 o;
        o.x = (h0 > 0.f) ? h0 : expm1f(h0);
        o.y = (h1 > 0.f) ? h1 : expm1f(h1);
        o.z = (h2 > 0.f) ? h2 : expm1f(h2);
        o.w = (h3 > 0.f) ? h3 : expm1f(h3);
        ((float4*)out)[(size_t)n * 16 + c] = o;
    }
}

extern "C" void kernel_launch(void* const* d_in, const int* in_sizes, int n_in,
                              void* d_out, int out_size, void* d_ws, size_t ws_size,
                              hipStream_t stream)
{
    const float* x     = (const float*)d_in[0];
    const int*   edge  = (const int*)d_in[1];
    // d_in[2] = edge_embed: unused by the reference computation
    const int*   etype = (const int*)d_in[3];
    const float* G     = (const float*)d_in[4];
    const float* a     = (const float*)d_in[5];
    const float* a2    = (const float*)d_in[6];

    const int N = in_sizes[0] / 64;   // 50000  (packing needs N < 2^24)
    const int E = in_sizes[1] / 2;    // 800000
    const int R = in_sizes[4] / N;    // 200    (packing needs R <= 256)

    float* out = (float*)d_out;

    // workspace layout (~20 MB):
    // u_bf[N*64] | v_bf[N*64] (bf16) | su[N] | sv[N] | count[N] | base[N] |
    // blocksums[nsb] | rank[E] | csr[E] (uint32)
    __hip_bfloat16* u_bf = (__hip_bfloat16*)d_ws;
    __hip_bfloat16* v_bf = u_bf + (size_t)N * 64;
    float* su     = (float*)(v_bf + (size_t)N * 64);
    float* sv     = su + N;
    int*   count  = (int*)(sv + N);
    int*   base   = count + N;
    const int nsb = (N + SCAN_TILE - 1) / SCAN_TILE;
    int*   blocksums = base + N;
    int*   rank   = blocksums + ((nsb + 63) & ~63);
    unsigned int* csr = (unsigned int*)(rank + E);

    node_transform_kernel<<<dim3((N + 3) / 4), dim3(256), 0, stream>>>(
        x, a, a2, u_bf, v_bf, su, sv, count, N);
    hist_kernel<<<dim3(((E + 3) / 4 + 255) / 256), dim3(256), 0, stream>>>(
        edge, count, rank, E);
    scan_blocks_kernel<<<dim3(nsb), dim3(SCAN_BLOCK), 0, stream>>>(count, base, blocksums, N);
    scan_tops_kernel<<<dim3(1), dim3(64), 0, stream>>>(blocksums, nsb);
    edge_place_kernel<<<dim3((E + 255) / 256), dim3(256), 0, stream>>>(
        edge, etype, base, blocksums, rank, csr, E, N, R);
    aggregate_kernel<<<dim3((N + 3) / 4), dim3(256), 0, stream>>>(
        base, blocksums, csr, (const uint2*)u_bf, (const uint2*)v_bf,
        su, sv, G, R, out, N, E);
}